// Round 14
// baseline (95.166 us; speedup 1.0000x reference)
//
#include <hip/hip_runtime.h>
#include <hip/hip_bf16.h>

using bf16 = __hip_bfloat16;
typedef __attribute__((ext_vector_type(8))) short bf16x8;
typedef __attribute__((ext_vector_type(4))) float f32x4;

#define MFMA16(a, b, c) __builtin_amdgcn_mfma_f32_16x16x32_bf16(a, b, c, 0, 0, 0)
// XOR swizzle: spreads 8 rows of a 128B-stride tile across 8 16B slots
#define SWZ(row, byteoff) ((byteoff) ^ (((row) & 7) << 4))
// 64B-row variant: spreads rows across 4 16B slots (residual 2-way = free)
#define SWZ64(row, byteoff) ((byteoff) ^ ((((row) >> 1) & 3) << 4))

__device__ __forceinline__ unsigned short f2b(float f) {
  union { float f; unsigned int u; } c; c.f = f;
  unsigned int r = c.u + 0x7fffu + ((c.u >> 16) & 1u);
  return (unsigned short)(r >> 16);
}
__device__ __forceinline__ float b2f(short b) {
  union { unsigned int u; float f; } c;
  c.u = ((unsigned int)(unsigned short)b) << 16;
  return c.f;
}
__device__ __forceinline__ bf16x8 scale8(bf16x8 v, float s) {
  bf16x8 r;
#pragma unroll
  for (int j = 0; j < 8; ++j) r[j] = (short)f2b(b2f(v[j]) * s);
  return r;
}
// packed f32x2 -> bf16x2 (T12 recipe: no builtin on gfx950, inline asm; RNE)
__device__ __forceinline__ unsigned cvtpk(float a, float b) {
  unsigned r;
  asm("v_cvt_pk_bf16_f32 %0, %1, %2" : "=v"(r) : "v"(a), "v"(b));
  return r;
}

__device__ __forceinline__ void gload_lds16(const void* g, void* l) {
  __builtin_amdgcn_global_load_lds(
      (const __attribute__((address_space(1))) void*)g,
      (__attribute__((address_space(3))) void*)l, 16, 0, 0);
}

// ---------------- cast fp32 -> bf16 (x + 4 weights) ----------------
__global__ __launch_bounds__(256) void cast_all(
    const float* __restrict__ x, const float* __restrict__ wq,
    const float* __restrict__ wk, const float* __restrict__ wv,
    const float* __restrict__ wo,
    unsigned short* __restrict__ xb, unsigned short* __restrict__ wqb,
    unsigned short* __restrict__ wkb, unsigned short* __restrict__ wvb,
    unsigned short* __restrict__ wob) {
  int i = blockIdx.x * 256 + threadIdx.x;  // float4 units, 2097152 total
  const float* src;
  unsigned short* dst;
  int off;
  if (i < 1048576) {
    src = x; dst = xb; off = i;
  } else {
    int j = i - 1048576;
    int seg = j >> 18;
    off = j & 262143;
    src = (seg == 0) ? wq : (seg == 1) ? wk : (seg == 2) ? wv : wo;
    dst = (seg == 0) ? wqb : (seg == 1) ? wkb : (seg == 2) ? wvb : wob;
  }
  float4 v = reinterpret_cast<const float4*>(src)[off];
  ushort4 o;
  o.x = f2b(v.x); o.y = f2b(v.y); o.z = f2b(v.z); o.w = f2b(v.w);
  reinterpret_cast<ushort4*>(dst)[off] = o;
}

// ============ fused QKV GEMM: 256x256 tile, 8-phase counted-vmcnt ==========
// M=4096, N=3072 (wq||wk||wv), K=1024. 512 threads (8 waves, 2Mx4N), per-wave
// 128x64 output. LDS: per operand 4 K-half slots (256 rows x 32 cols, 16KB);
// slot(t,kh) = (2t+kh)&3. Per tile t: 4 phases (kh,nh); each phase:
// {ds_read frags; issue 1 stage-quantum (2 gload_lds); s_barrier; lgkmcnt(0)
// + sched_barrier (rule 18); setprio(1); 16 MFMA; setprio(0)}.
// Issue schedule: ph0->A(t+1,1), ph1->B(t+1,1), ph2->A(t+2,0), ph3->B(t+2,0).
// vmcnt(8) (never 0 until the tail) at end of ph1 and ph3: the 8 newest loads
// are exactly the 4 not-yet-needed quanta; everything older has landed.
// 64B-row XOR swizzle (2-way residual = free, m136). Same FP accumulation
// order as the BK=64 2-phase kernel -> bit-identical C.
__global__ __launch_bounds__(512, 2) void gemm_qkv8(
    const bf16* __restrict__ A, const bf16* __restrict__ B3,
    bf16* __restrict__ Cq, bf16* __restrict__ Ck, bf16* __restrict__ Cv) {
  __shared__ bf16 As[4][256 * 32];  // 64 KB
  __shared__ bf16 Bs[4][256 * 32];  // 64 KB
  const int tid = threadIdx.x;
  const int lane = tid & 63;
  const int w = tid >> 6;
  const int wr = w >> 2;   // 0..1  M-half
  const int wc = w & 3;    // 0..3  N-quarter
  const int fr = lane & 15;
  const int fg = lane >> 4;

  const int id = blockIdx.y * 16 + blockIdx.x;  // 0..191
  const int sw = (id & 7) * 24 + (id >> 3);     // bijective XCD chunking
  const int bm = (sw & 15) * 256;
  const int bnG = (sw >> 4) * 256;
  const bf16* Bt = B3 + (size_t)bnG * 1024;
  bf16* C = (bnG < 1024) ? Cq : (bnG < 2048) ? Ck : Cv;
  const int bn = bnG & 1023;

  const int srow = tid >> 2;       // staging row within 128-row round
  const int scb = (tid & 3) * 16;  // 16B slot within 64B row

  f32x4 acc[8][4] = {};

  // stage one K-half quantum (256 rows x 32 cols) of tile t into slot s.
  // LDS dest linear (tid*16); global source pre-inverse-swizzled (involution).
#define QST(P, RB, t, kh, s, ARR)                                            \
  {                                                                          \
    _Pragma("unroll") for (int rr = 0; rr < 2; ++rr) {                       \
      const int row = rr * 128 + srow;                                       \
      gload_lds16((const char*)(P) +                                         \
                      ((size_t)((RB) + row) * 1024 + (t)*64 + (kh)*32) * 2 + \
                      SWZ64(row, scb),                                       \
                  (char*)&ARR[s][0] + rr * 8192 + tid * 16);                 \
    }                                                                        \
  }
#define AFR(s, m)                                                           \
  (*(const bf16x8*)((const char*)&As[s][0] +                                \
                    (wr * 128 + (m)*16 + fr) * 64 +                         \
                    SWZ64(wr * 128 + (m)*16 + fr, fg * 16)))
#define BFR(s, n)                                                           \
  (*(const bf16x8*)((const char*)&Bs[s][0] +                                \
                    (wc * 64 + (n)*16 + fr) * 64 +                          \
                    SWZ64(wc * 64 + (n)*16 + fr, fg * 16)))
#define LGKM0                                             \
  asm volatile("s_waitcnt lgkmcnt(0)" ::: "memory");      \
  __builtin_amdgcn_sched_barrier(0)

  // prologue: A(0,0) B(0,0) A(0,1) B(0,1) A(1,0) B(1,0) = 12 loads/thread
  QST(A, bm, 0, 0, 0, As);
  QST(Bt, 0, 0, 0, 0, Bs);
  QST(A, bm, 0, 1, 1, As);
  QST(Bt, 0, 0, 1, 1, Bs);
  QST(A, bm, 1, 0, 2, As);
  QST(Bt, 0, 1, 0, 2, Bs);
  asm volatile("s_waitcnt vmcnt(8)" ::: "memory");  // tile-0 kh0 landed
  __builtin_amdgcn_sched_barrier(0);
  __builtin_amdgcn_s_barrier();

  for (int t = 0; t < 16; ++t) {
    const int s0 = (2 * t) & 3, s1 = (2 * t + 1) & 3;
    const int sn1 = (2 * t + 3) & 3;  // slot for (t+1, kh1)
    const int sn2 = (2 * t + 4) & 3;  // slot for (t+2, kh0)
    bf16x8 af[8], b0, b1;

    // -------- phase 0: kh=0, n-half 0; issue A(t+1,1) --------
#pragma unroll
    for (int m = 0; m < 8; ++m) af[m] = AFR(s0, m);
    b0 = BFR(s0, 0);
    b1 = BFR(s0, 1);
    if (t < 15) QST(A, bm, t + 1, 1, sn1, As);
    __builtin_amdgcn_s_barrier();
    LGKM0;
    __builtin_amdgcn_s_setprio(1);
#pragma unroll
    for (int m = 0; m < 8; ++m) {
      acc[m][0] = MFMA16(af[m], b0, acc[m][0]);
      acc[m][1] = MFMA16(af[m], b1, acc[m][1]);
    }
    __builtin_amdgcn_s_setprio(0);
    __builtin_amdgcn_s_barrier();

    // -------- phase 1: kh=0, n-half 1; issue B(t+1,1) --------
    b0 = BFR(s0, 2);
    b1 = BFR(s0, 3);
    if (t < 15) QST(Bt, 0, t + 1, 1, sn1, Bs);
    __builtin_amdgcn_s_barrier();
    LGKM0;
    __builtin_amdgcn_s_setprio(1);
#pragma unroll
    for (int m = 0; m < 8; ++m) {
      acc[m][2] = MFMA16(af[m], b0, acc[m][2]);
      acc[m][3] = MFMA16(af[m], b1, acc[m][3]);
    }
    __builtin_amdgcn_s_setprio(0);
    if (t < 15) {
      asm volatile("s_waitcnt vmcnt(8)" ::: "memory");  // (t,kh1) landed
    } else {
      asm volatile("s_waitcnt vmcnt(0)" ::: "memory");
    }
    __builtin_amdgcn_sched_barrier(0);
    __builtin_amdgcn_s_barrier();

    // -------- phase 2: kh=1, n-half 0; issue A(t+2,0) --------
#pragma unroll
    for (int m = 0; m < 8; ++m) af[m] = AFR(s1, m);
    b0 = BFR(s1, 0);
    b1 = BFR(s1, 1);
    if (t < 14) QST(A, bm, t + 2, 0, sn2, As);
    __builtin_amdgcn_s_barrier();
    LGKM0;
    __builtin_amdgcn_s_setprio(1);
#pragma unroll
    for (int m = 0; m < 8; ++m) {
      acc[m][0] = MFMA16(af[m], b0, acc[m][0]);
      acc[m][1] = MFMA16(af[m], b1, acc[m][1]);
    }
    __builtin_amdgcn_s_setprio(0);
    __builtin_amdgcn_s_barrier();

    // -------- phase 3: kh=1, n-half 1; issue B(t+2,0) --------
    b0 = BFR(s1, 2);
    b1 = BFR(s1, 3);
    if (t < 14) QST(Bt, 0, t + 2, 0, sn2, Bs);
    __builtin_amdgcn_s_barrier();
    LGKM0;
    __builtin_amdgcn_s_setprio(1);
#pragma unroll
    for (int m = 0; m < 8; ++m) {
      acc[m][2] = MFMA16(af[m], b0, acc[m][2]);
      acc[m][3] = MFMA16(af[m], b1, acc[m][3]);
    }
    __builtin_amdgcn_s_setprio(0);
    if (t <= 13) {
      asm volatile("s_waitcnt vmcnt(8)" ::: "memory");  // (t+1,kh0) landed
      __builtin_amdgcn_sched_barrier(0);
      __builtin_amdgcn_s_barrier();
    } else if (t == 14) {
      asm volatile("s_waitcnt vmcnt(4)" ::: "memory");
      __builtin_amdgcn_sched_barrier(0);
      __builtin_amdgcn_s_barrier();
    }
    // t == 15: loop ends; no further shared reads
  }

#pragma unroll
  for (int m = 0; m < 8; ++m) {
    const int row0 = bm + wr * 128 + m * 16 + fg * 4;
#pragma unroll
    for (int n = 0; n < 4; ++n) {
      const int col = bn + wc * 64 + n * 16 + fr;
#pragma unroll
      for (int r = 0; r < 4; ++r)
        *(unsigned short*)&C[(size_t)(row0 + r) * 1024 + col] =
            f2b(acc[m][n][r]);
    }
  }
#undef QST
#undef AFR
#undef BFR
#undef LGKM0
}

// ---- out-proj: 128x64 tiles, 512 blocks -> 2 blocks/CU ----
__global__ __launch_bounds__(256) void gemm_out64(const bf16* __restrict__ A,
                                                  const bf16* __restrict__ B,
                                                  float* __restrict__ C) {
  __shared__ bf16 Asm[128 * 64];  // 16 KB
  __shared__ bf16 Bsm[64 * 64];   // 8 KB
  const int id = blockIdx.y * 32 + blockIdx.x;  // 0..511
  const int sw = (id & 7) * 64 + (id >> 3);     // bijective XCD chunking
  const int bm = (sw & 31) * 128;
  const int bn = (sw >> 5) * 64;
  const bf16* Bt = B + (size_t)bn * 1024;

  const int tid = threadIdx.x;
  const int lane = tid & 63;
  const int w = tid >> 6;
  const int wr = w >> 1, wc = w & 1;
  const int fr = lane & 15;
  const int fg = lane >> 4;
  f32x4 acc[4][2] = {};

  const int strow = w * 8 + (lane >> 3);
  const int stcb = (lane & 7) * 16;

  for (int kt = 0; kt < 1024; kt += 64) {
#pragma unroll
    for (int r = 0; r < 4; ++r) {
      const int row = r * 32 + strow;
      gload_lds16(
          (const char*)(A + (size_t)(bm + row) * 1024 + kt) + SWZ(row, stcb),
          (char*)Asm + (r * 32 + w * 8) * 128);
    }
#pragma unroll
    for (int r = 0; r < 2; ++r) {
      const int row = r * 32 + strow;
      gload_lds16(
          (const char*)(Bt + (size_t)row * 1024 + kt) + SWZ(row, stcb),
          (char*)Bsm + (r * 32 + w * 8) * 128);
    }
    __syncthreads();
    bf16x8 afr[4][2], bfr[2][2];
#pragma unroll
    for (int m = 0; m < 4; ++m) {
      const int row = wr * 64 + m * 16 + fr;
      const char* rp = (const char*)Asm + row * 128;
#pragma unroll
      for (int s = 0; s < 2; ++s)
        afr[m][s] = *(const bf16x8*)(rp + SWZ(row, s * 64 + fg * 16));
    }
#pragma unroll
    for (int n = 0; n < 2; ++n) {
      const int row = wc * 32 + n * 16 + fr;
      const char* rp = (const char*)Bsm + row * 128;
#pragma unroll
      for (int s = 0; s < 2; ++s)
        bfr[n][s] = *(const bf16x8*)(rp + SWZ(row, s * 64 + fg * 16));
    }
    __builtin_amdgcn_s_setprio(1);
#pragma unroll
    for (int m = 0; m < 4; ++m)
#pragma unroll
      for (int n = 0; n < 2; ++n) {
        acc[m][n] = MFMA16(afr[m][0], bfr[n][0], acc[m][n]);
        acc[m][n] = MFMA16(afr[m][1], bfr[n][1], acc[m][n]);
      }
    __builtin_amdgcn_s_setprio(0);
    __syncthreads();
  }
#pragma unroll
  for (int m = 0; m < 4; ++m) {
    const int row0 = bm + wr * 64 + m * 16 + fg * 4;
#pragma unroll
    for (int n = 0; n < 2; ++n) {
      const int col = bn + wc * 32 + n * 16 + fr;
#pragma unroll
      for (int r = 0; r < 4; ++r)
        C[(size_t)(row0 + r) * 1024 + col] = acc[m][n][r];
    }
  }
}

// ---------------- causal flash attention, KVBLK=128 (R13, proven) ----------
__global__ __launch_bounds__(256) void attn_fwd(
    const bf16* __restrict__ Q, const bf16* __restrict__ K,
    const bf16* __restrict__ V, bf16* __restrict__ O) {
  const int nh = blockIdx.x;  // head-major
  const size_t base = (size_t)nh * 65536;  // 1024*64 contiguous per head
  const bf16* Qp = Q + base;
  const bf16* Kp = K + base;
  const bf16* Vp = V + base;
  bf16* Op = O + base;
  const int p = blockIdx.y;  // pair 0..7
  const int qiA = p, qiB = 15 - p;
  const int tid = threadIdx.x;
  const int lane = tid & 63;
  const int w = tid >> 6;
  const int fr = lane & 15;
  const int fg = lane >> 4;

  __shared__ bf16 Ksm[2][2][64 * 64];  // [buf][slot][kv][d], swizzled
  __shared__ bf16 Vts[2][2][64 * 64];  // [buf][slot][d][kv], swizzled

  const float QSC = 0.125f * 1.44269504089f;  // exp2 domain
  const float MS = 12.0f;                     // static softmax shift
  const int rA0 = qiA * 64 + w * 16;
  const int rB0 = qiB * 64 + w * 16;
  bf16x8 qA[2], qB[2];
#pragma unroll
  for (int ks = 0; ks < 2; ++ks) {
    qA[ks] = scale8(
        *(const bf16x8*)&Qp[(size_t)(rA0 + fr) * 64 + ks * 32 + fg * 8], QSC);
    qB[ks] = scale8(
        *(const bf16x8*)&Qp[(size_t)(rB0 + fr) * 64 + ks * 32 + fg * 8], QSC);
  }

  float sA = 0.f, sB = 0.f;  // per-lane partial row-sum (row q = fr)
  f32x4 oA[4], oB[4];
#pragma unroll
  for (int d = 0; d < 4; ++d) {
    oA[d] = (f32x4){0.f, 0.f, 0.f, 0.f};
    oB[d] = (f32x4){0.f, 0.f, 0.f, 0.f};
  }

  const int NKV = qiB + 1;       // 9..16
  const int qloc = w * 16 + fr;  // tile-relative q-row of this lane

  // V transpose thread mapping
  const int bkv = (tid & 15) * 4;
  const int bd = (tid >> 4) * 4;
  union VU { ushort4 v; unsigned short s[4]; };
  VU v4a[4], v4b[4];

  const int krow = w * 16 + (lane >> 3);
  const int kcb = (lane & 7) * 16;

#define STAGE_K(kt, dst)                                                      \
  {                                                                           \
    _Pragma("unroll") for (int i = 0; i < 2; ++i) {                           \
      const int row = krow + i * 8;                                           \
      gload_lds16((const char*)Kp + ((size_t)((kt)*64 + row) * 128 +          \
                                     SWZ(row, kcb)),                          \
                  (char*)(dst) + (w * 16 + i * 8) * 128);                     \
    }                                                                         \
  }
#define LOAD_V(kt, r)                                                         \
  {                                                                           \
    _Pragma("unroll") for (int j = 0; j < 4; ++j) (r)[j].v =                  \
        *(const ushort4*)(Vp + (size_t)((kt)*64 + bkv + j) * 64 + bd);        \
  }
#define WRITE_V(dst, r)                                                       \
  {                                                                           \
    _Pragma("unroll") for (int i = 0; i < 4; ++i) {                           \
      VU o4;                                                                  \
      _Pragma("unroll") for (int j = 0; j < 4; ++j) o4.s[j] = (r)[j].s[i];    \
      const int row = bd + i;                                                 \
      *(ushort4*)((char*)(dst) + row * 128 + SWZ(row, bkv * 2)) = o4.v;       \
    }                                                                         \
  }

  union PU { bf16x8 v; unsigned u[4]; };
  union VF { bf16x8 v; unsigned long long q[2]; };

  auto compute_tile = [&](int kt, const char* kb, const char* vb) {
    const bool aAct = (kt <= qiA);
    bf16x8 kf[4][2];
#pragma unroll
    for (int c = 0; c < 4; ++c) {
      const int row = c * 16 + fr;
      const char* rp = kb + row * 128;
      kf[c][0] = *(const bf16x8*)(rp + SWZ(row, fg * 16));
      kf[c][1] = *(const bf16x8*)(rp + SWZ(row, 64 + fg * 16));
    }
    VF vf[4][2];
#pragma unroll
    for (int d = 0; d < 4; ++d) {
      const int row = d * 16 + fr;
      const char* rp = vb + row * 128;
#pragma unroll
      for (int ks = 0; ks < 2; ++ks) {
        vf[d][ks].q[0] =
            *(const unsigned long long*)(rp + SWZ(row, ks * 64 + fg * 8));
        vf[d][ks].q[1] =
            *(const unsigned long long*)(rp + SWZ(row, ks * 64 + 32 + fg * 8));
      }
    }

    auto strip_sm = [&](const bf16x8 (&qf)[2], float& s, bool diag,
                        PU (&pa)[2]) {
      f32x4 sc[4];
      __builtin_amdgcn_s_setprio(1);
#pragma unroll
      for (int c = 0; c < 4; ++c) {
        f32x4 acc = (f32x4){0.f, 0.f, 0.f, 0.f};
        acc = MFMA16(kf[c][0], qf[0], acc);  // C[kv][q]
        acc = MFMA16(kf[c][1], qf[1], acc);
        sc[c] = acc;
      }
      __builtin_amdgcn_s_setprio(0);
      float pv[4][4];
#pragma unroll
      for (int c = 0; c < 4; ++c)
#pragma unroll
        for (int r = 0; r < 4; ++r) {
          float sv = sc[c][r];
          if (diag) {
            const int kvloc = c * 16 + fg * 4 + r;
            sv = (kvloc <= qloc) ? sv : -INFINITY;
          }
          const float e = __builtin_amdgcn_exp2f(sv - MS);
          pv[c][r] = e;
          s += e;
        }
#pragma unroll
      for (int ks = 0; ks < 2; ++ks) {
        pa[ks].u[0] = cvtpk(pv[ks * 2][0], pv[ks * 2][1]);
        pa[ks].u[1] = cvtpk(pv[ks * 2][2], pv[ks * 2][3]);
        pa[ks].u[2] = cvtpk(pv[ks * 2 + 1][0], pv[ks * 2 + 1][1]);
        pa[ks].u[3] = cvtpk(pv[ks * 2 + 1][2], pv[ks * 2 + 1][3]);
      }
    };

    PU paA[2], paB[2];
    strip_sm(qB, sB, kt == qiB, paB);
    if (aAct) strip_sm(qA, sA, kt == qiA, paA);

    __builtin_amdgcn_s_setprio(1);
#pragma unroll
    for (int d = 0; d < 4; ++d) {
      oB[d] = MFMA16(paB[0].v, vf[d][0].v, oB[d]);
      oB[d] = MFMA16(paB[1].v, vf[d][1].v, oB[d]);
    }
    if (aAct) {
#pragma unroll
      for (int d = 0; d < 4; ++d) {
        oA[d] = MFMA16(paA[0].v, vf[d][0].v, oA[d]);
        oA[d] = MFMA16(paA[1].v, vf[d][1].v, oA[d]);
      }
    }
    __builtin_amdgcn_s_setprio(0);
  };

  // prologue: stage tiles 0,1 into buf 0 (NKV >= 9, both exist)
  STAGE_K(0, &Ksm[0][0][0]);
  STAGE_K(1, &Ksm[0][1][0]);
  LOAD_V(0, v4a);
  LOAD_V(1, v4b);
  WRITE_V(&Vts[0][0][0], v4a);
  WRITE_V(&Vts[0][1][0], v4b);
  __syncthreads();

  const int I = (NKV + 1) >> 1;
  for (int it = 0; it < I; ++it) {
    const int kt0 = 2 * it;
    const int b = it & 1;
    const bool more0 = (kt0 + 2 < NKV);
    const bool more1 = (kt0 + 3 < NKV);
    if (more0) {
      STAGE_K(kt0 + 2, &Ksm[b ^ 1][0][0]);
      LOAD_V(kt0 + 2, v4a);
    }
    if (more1) {
      STAGE_K(kt0 + 3, &Ksm[b ^ 1][1][0]);
      LOAD_V(kt0 + 3, v4b);
    }

    compute_tile(kt0, (const char*)&Ksm[b][0][0], (const char*)&Vts[b][0][0]);
    if (kt0 + 1 < NKV)
      compute_tile(kt0 + 1, (const char*)&Ksm[b][1][0],
                   (const char*)&Vts[b][1][0]);

    if (more0) WRITE_V(&Vts[b ^ 1][0][0], v4a);
    if (more1) WRITE_V(&Vts[b ^ 1][1][0], v4b);
    __syncthreads();
  }

  // ---- reduce row sums across fg groups: lane (*, fr) -> s[q=fr] ----
  sA += __shfl_xor(sA, 16); sA += __shfl_xor(sA, 32);
  sB += __shfl_xor(sB, 16); sB += __shfl_xor(sB, 32);
  float sAo[4], sBo[4];
#pragma unroll
  for (int r = 0; r < 4; ++r) {
    sAo[r] = __shfl(sA, fg * 4 + r);
    sBo[r] = __shfl(sB, fg * 4 + r);
  }

#pragma unroll
  for (int d = 0; d < 4; ++d)
#pragma unroll
    for (int r = 0; r < 4; ++r) {
      const float vA = oA[d][r] / sAo[r];
      const float vB = oB[d][r] / sBo[r];
      *(unsigned short*)&Op[(size_t)(rA0 + fg * 4 + r) * 64 + d * 16 + fr] =
          f2b(vA);
      *(unsigned short*)&Op[(size_t)(rB0 + fg * 4 + r) * 64 + d * 16 + fr] =
          f2b(vB);
    }
#undef STAGE_K
#undef LOAD_V
#undef WRITE_V
}

extern "C" void kernel_launch(void* const* d_in, const int* in_sizes, int n_in,
                              void* d_out, int out_size, void* d_ws,
                              size_t ws_size, hipStream_t stream) {
  const float* x = (const float*)d_in[0];
  const float* wq = (const float*)d_in[1];
  const float* wk = (const float*)d_in[2];
  const float* wv = (const float*)d_in[3];
  const float* wo = (const float*)d_in[4];
  float* out = (float*)d_out;
  char* ws = (char*)d_ws;

  bf16* xb = (bf16*)(ws);                  // 8 MB (4096x1024)
  bf16* wqkv = (bf16*)(ws + (8u << 20));   // 6 MB: wq|wk|wv = [3072][1024]
  bf16* wqb = wqkv;
  bf16* wkb = (bf16*)(ws + (10u << 20));
  bf16* wvb = (bf16*)(ws + (12u << 20));
  bf16* wob = (bf16*)(ws + (14u << 20));   // 2 MB
  bf16* qbuf = (bf16*)(ws + (16u << 20));  // 8 MB
  bf16* kbuf = (bf16*)(ws + (24u << 20));  // 8 MB
  bf16* vbuf = (bf16*)(ws + (32u << 20));  // 8 MB
  bf16* weib = (bf16*)(ws);                // reuse xb region after QKV GEMM

  cast_all<<<8192, 256, 0, stream>>>(x, wq, wk, wv, wo, (unsigned short*)xb,
                                     (unsigned short*)wqb, (unsigned short*)wkb,
                                     (unsigned short*)wvb, (unsigned short*)wob);
  gemm_qkv8<<<dim3(16, 12), 512, 0, stream>>>(xb, wqkv, qbuf, kbuf, vbuf);
  attn_fwd<<<dim3(64, 8), 256, 0, stream>>>(qbuf, kbuf, vbuf, weib);
  gemm_out64<<<dim3(32, 16), 256, 0, stream>>>(weib, wob, out);
}

// Round 15
// 84.997 us; speedup vs baseline: 1.1196x; 1.1196x over previous
//
#include <hip/hip_runtime.h>
#include <hip/hip_bf16.h>

using bf16 = __hip_bfloat16;
typedef __attribute__((ext_vector_type(8))) short bf16x8;
typedef __attribute__((ext_vector_type(4))) float f32x4;

#define MFMA16(a, b, c) __builtin_amdgcn_mfma_f32_16x16x32_bf16(a, b, c, 0, 0, 0)
// XOR swizzle: spreads 8 rows of a 128B-stride tile across 8 16B slots
#define SWZ(row, byteoff) ((byteoff) ^ (((row) & 7) << 4))

__device__ __forceinline__ unsigned short f2b(float f) {
  union { float f; unsigned int u; } c; c.f = f;
  unsigned int r = c.u + 0x7fffu + ((c.u >> 16) & 1u);
  return (unsigned short)(r >> 16);
}
__device__ __forceinline__ float b2f(short b) {
  union { unsigned int u; float f; } c;
  c.u = ((unsigned int)(unsigned short)b) << 16;
  return c.f;
}
__device__ __forceinline__ bf16x8 scale8(bf16x8 v, float s) {
  bf16x8 r;
#pragma unroll
  for (int j = 0; j < 8; ++j) r[j] = (short)f2b(b2f(v[j]) * s);
  return r;
}
// packed f32x2 -> bf16x2 (T12 recipe: no builtin on gfx950, inline asm; RNE)
__device__ __forceinline__ unsigned cvtpk(float a, float b) {
  unsigned r;
  asm("v_cvt_pk_bf16_f32 %0, %1, %2" : "=v"(r) : "v"(a), "v"(b));
  return r;
}

__device__ __forceinline__ void gload_lds16(const void* g, void* l) {
  __builtin_amdgcn_global_load_lds(
      (const __attribute__((address_space(1))) void*)g,
      (__attribute__((address_space(3))) void*)l, 16, 0, 0);
}

__device__ __forceinline__ void store_out(float* p, float v) { *p = v; }
__device__ __forceinline__ void store_out(bf16* p, float v) {
  *(unsigned short*)p = f2b(v);
}

// ---------------- cast fp32 -> bf16 (x + 4 weights) ----------------
__global__ __launch_bounds__(256) void cast_all(
    const float* __restrict__ x, const float* __restrict__ wq,
    const float* __restrict__ wk, const float* __restrict__ wv,
    const float* __restrict__ wo,
    unsigned short* __restrict__ xb, unsigned short* __restrict__ wqb,
    unsigned short* __restrict__ wkb, unsigned short* __restrict__ wvb,
    unsigned short* __restrict__ wob) {
  int i = blockIdx.x * 256 + threadIdx.x;  // float4 units, 2097152 total
  const float* src;
  unsigned short* dst;
  int off;
  if (i < 1048576) {
    src = x; dst = xb; off = i;
  } else {
    int j = i - 1048576;
    int seg = j >> 18;
    off = j & 262143;
    src = (seg == 0) ? wq : (seg == 1) ? wk : (seg == 2) ? wv : wo;
    dst = (seg == 0) ? wqb : (seg == 1) ? wkb : (seg == 2) ? wvb : wob;
  }
  float4 v = reinterpret_cast<const float4*>(src)[off];
  ushort4 o;
  o.x = f2b(v.x); o.y = f2b(v.y); o.z = f2b(v.z); o.w = f2b(v.w);
  reinterpret_cast<ushort4*>(dst)[off] = o;
}

// ------- GEMM tile body: C[128][128] = A-rows @ Bt-rows^T, BK=64 ----------
// 128B LDS rows, XOR-swizzled (pre-swizzled global_load_lds source + swizzled
// ds_read_b128). 32 MFMA per barrier-pair. (Session plateau structure: both
// deep-pipeline attempts (R6, R14) regressed — do not re-derive.)
template <typename TOUT>
__device__ __forceinline__ void gemm_tile(const bf16* __restrict__ A,
                                          const bf16* __restrict__ Bt,
                                          TOUT* __restrict__ C, int N, int K,
                                          int bm, int bn) {
  __shared__ bf16 Asm[128 * 64];  // 16 KB each
  __shared__ bf16 Bsm[128 * 64];
  const int tid = threadIdx.x;
  const int lane = tid & 63;
  const int w = tid >> 6;
  const int wr = w >> 1, wc = w & 1;
  const int fr = lane & 15;
  const int fg = lane >> 4;
  f32x4 acc[4][4] = {};

  const int strow = w * 8 + (lane >> 3);  // staging row within 32-row round
  const int stcb = (lane & 7) * 16;       // linear 16B slot within 128B row

  for (int kt = 0; kt < K; kt += 64) {
#pragma unroll
    for (int r = 0; r < 4; ++r) {
      const int row = r * 32 + strow;
      gload_lds16(
          (const char*)(A + (size_t)(bm + row) * K + kt) + SWZ(row, stcb),
          (char*)Asm + (r * 32 + w * 8) * 128);
      gload_lds16(
          (const char*)(Bt + (size_t)row * K + kt) + SWZ(row, stcb),
          (char*)Bsm + (r * 32 + w * 8) * 128);
    }
    __syncthreads();
    bf16x8 afr[4][2], bfr[4][2];
#pragma unroll
    for (int m = 0; m < 4; ++m) {
      const int row = wr * 64 + m * 16 + fr;
      const char* rp = (const char*)Asm + row * 128;
#pragma unroll
      for (int s = 0; s < 2; ++s)
        afr[m][s] = *(const bf16x8*)(rp + SWZ(row, s * 64 + fg * 16));
    }
#pragma unroll
    for (int n = 0; n < 4; ++n) {
      const int row = wc * 64 + n * 16 + fr;
      const char* rp = (const char*)Bsm + row * 128;
#pragma unroll
      for (int s = 0; s < 2; ++s)
        bfr[n][s] = *(const bf16x8*)(rp + SWZ(row, s * 64 + fg * 16));
    }
    __builtin_amdgcn_s_setprio(1);
#pragma unroll
    for (int m = 0; m < 4; ++m)
#pragma unroll
      for (int n = 0; n < 4; ++n) {
        acc[m][n] = MFMA16(afr[m][0], bfr[n][0], acc[m][n]);
        acc[m][n] = MFMA16(afr[m][1], bfr[n][1], acc[m][n]);
      }
    __builtin_amdgcn_s_setprio(0);
    __syncthreads();
  }
#pragma unroll
  for (int m = 0; m < 4; ++m) {
    const int row0 = bm + wr * 64 + m * 16 + (lane >> 4) * 4;
#pragma unroll
    for (int n = 0; n < 4; ++n) {
      const int col = bn + wc * 64 + n * 16 + fr;
#pragma unroll
      for (int r = 0; r < 4; ++r)
        store_out(&C[(size_t)(row0 + r) * N + col], acc[m][n][r]);
    }
  }
}

// fused QKV: B3 = [3072][1024]; XCD-swizzled grid (768 blocks, 768%8==0)
__global__ __launch_bounds__(256) void gemm_qkv(
    const bf16* __restrict__ A, const bf16* __restrict__ B3,
    bf16* __restrict__ Cq, bf16* __restrict__ Ck, bf16* __restrict__ Cv) {
  const int id = blockIdx.y * 32 + blockIdx.x;   // 0..767
  const int sw = (id & 7) * 96 + (id >> 3);      // bijective XCD chunking
  const int bm = (sw & 31) * 128;
  const int bnG = (sw >> 5) * 128;
  bf16* C = (bnG < 1024) ? Cq : (bnG < 2048) ? Ck : Cv;
  gemm_tile<bf16>(A, B3 + (size_t)bnG * 1024, C, 1024, 1024, bm, bnG & 1023);
}

// ---- out-proj: 128x64 tiles, 512 blocks -> 2 blocks/CU ----
__global__ __launch_bounds__(256) void gemm_out64(const bf16* __restrict__ A,
                                                  const bf16* __restrict__ B,
                                                  float* __restrict__ C) {
  __shared__ bf16 Asm[128 * 64];  // 16 KB
  __shared__ bf16 Bsm[64 * 64];   // 8 KB
  const int id = blockIdx.y * 32 + blockIdx.x;  // 0..511
  const int sw = (id & 7) * 64 + (id >> 3);     // bijective XCD chunking
  const int bm = (sw & 31) * 128;
  const int bn = (sw >> 5) * 64;
  const bf16* Bt = B + (size_t)bn * 1024;

  const int tid = threadIdx.x;
  const int lane = tid & 63;
  const int w = tid >> 6;
  const int wr = w >> 1, wc = w & 1;
  const int fr = lane & 15;
  const int fg = lane >> 4;
  f32x4 acc[4][2] = {};

  const int strow = w * 8 + (lane >> 3);
  const int stcb = (lane & 7) * 16;

  for (int kt = 0; kt < 1024; kt += 64) {
#pragma unroll
    for (int r = 0; r < 4; ++r) {
      const int row = r * 32 + strow;
      gload_lds16(
          (const char*)(A + (size_t)(bm + row) * 1024 + kt) + SWZ(row, stcb),
          (char*)Asm + (r * 32 + w * 8) * 128);
    }
#pragma unroll
    for (int r = 0; r < 2; ++r) {
      const int row = r * 32 + strow;
      gload_lds16(
          (const char*)(Bt + (size_t)row * 1024 + kt) + SWZ(row, stcb),
          (char*)Bsm + (r * 32 + w * 8) * 128);
    }
    __syncthreads();
    bf16x8 afr[4][2], bfr[2][2];
#pragma unroll
    for (int m = 0; m < 4; ++m) {
      const int row = wr * 64 + m * 16 + fr;
      const char* rp = (const char*)Asm + row * 128;
#pragma unroll
      for (int s = 0; s < 2; ++s)
        afr[m][s] = *(const bf16x8*)(rp + SWZ(row, s * 64 + fg * 16));
    }
#pragma unroll
    for (int n = 0; n < 2; ++n) {
      const int row = wc * 32 + n * 16 + fr;
      const char* rp = (const char*)Bsm + row * 128;
#pragma unroll
      for (int s = 0; s < 2; ++s)
        bfr[n][s] = *(const bf16x8*)(rp + SWZ(row, s * 64 + fg * 16));
    }
    __builtin_amdgcn_s_setprio(1);
#pragma unroll
    for (int m = 0; m < 4; ++m)
#pragma unroll
      for (int n = 0; n < 2; ++n) {
        acc[m][n] = MFMA16(afr[m][0], bfr[n][0], acc[m][n]);
        acc[m][n] = MFMA16(afr[m][1], bfr[n][1], acc[m][n]);
      }
    __builtin_amdgcn_s_setprio(0);
    __syncthreads();
  }
#pragma unroll
  for (int m = 0; m < 4; ++m) {
    const int row0 = bm + wr * 64 + m * 16 + fg * 4;
#pragma unroll
    for (int n = 0; n < 2; ++n) {
      const int col = bn + wc * 32 + n * 16 + fr;
#pragma unroll
      for (int r = 0; r < 4; ++r)
        C[(size_t)(row0 + r) * 1024 + col] = acc[m][n][r];
    }
  }
}

// ---------------- causal flash attention, KVBLK=128 ----------------
// R13 structure (proven). V^T LDS columns stored with per-4-kv permutation
// sigma(kv) = (c>>1)*32 + f*8 + (c&1)*4 + r  (c=kv>>4, f=(kv>>2)&3, r=kv&3)
// so each PV B-fragment (8 elems) is byte-contiguous: the 16 ds_read_b64
// per tile become 8 ds_read_b128 with the same conflict-free SWZ pattern as
// the K reads. P-pack order and MFMA slot assignment unchanged -> identical
// math. Static-M softmax exp2(S*log2e-12); swapped QK^T; in-register P.
__global__ __launch_bounds__(256) void attn_fwd(
    const bf16* __restrict__ Q, const bf16* __restrict__ K,
    const bf16* __restrict__ V, bf16* __restrict__ O) {
  const int nh = blockIdx.x;  // head-major
  const size_t base = (size_t)nh * 65536;  // 1024*64 contiguous per head
  const bf16* Qp = Q + base;
  const bf16* Kp = K + base;
  const bf16* Vp = V + base;
  bf16* Op = O + base;
  const int p = blockIdx.y;  // pair 0..7
  const int qiA = p, qiB = 15 - p;
  const int tid = threadIdx.x;
  const int lane = tid & 63;
  const int w = tid >> 6;
  const int fr = lane & 15;
  const int fg = lane >> 4;

  __shared__ __align__(16) bf16 Ksm[2][2][64 * 64];  // [buf][slot][kv][d]
  __shared__ __align__(16) bf16 Vts[2][2][64 * 64];  // [buf][slot][d][sigma]

  const float QSC = 0.125f * 1.44269504089f;  // exp2 domain
  const float MS = 12.0f;                     // static softmax shift
  const int rA0 = qiA * 64 + w * 16;
  const int rB0 = qiB * 64 + w * 16;
  bf16x8 qA[2], qB[2];
#pragma unroll
  for (int ks = 0; ks < 2; ++ks) {
    qA[ks] = scale8(
        *(const bf16x8*)&Qp[(size_t)(rA0 + fr) * 64 + ks * 32 + fg * 8], QSC);
    qB[ks] = scale8(
        *(const bf16x8*)&Qp[(size_t)(rB0 + fr) * 64 + ks * 32 + fg * 8], QSC);
  }

  float sA = 0.f, sB = 0.f;  // per-lane partial row-sum (row q = fr)
  f32x4 oA[4], oB[4];
#pragma unroll
  for (int d = 0; d < 4; ++d) {
    oA[d] = (f32x4){0.f, 0.f, 0.f, 0.f};
    oB[d] = (f32x4){0.f, 0.f, 0.f, 0.f};
  }

  const int NKV = qiB + 1;       // 9..16
  const int qloc = w * 16 + fr;  // tile-relative q-row of this lane

  // V transpose thread mapping; sigma-permuted column base for the 4-kv group
  const int bkv = (tid & 15) * 4;
  const int bd = (tid >> 4) * 4;
  // sigma byte col of group: c=bkv>>4, f=(bkv>>2)&3 -> (c>>1)*64+f*16+(c&1)*8
  const int sbk = ((bkv >> 5) << 6) + (((bkv >> 2) & 3) << 4) +
                  (((bkv >> 4) & 1) << 3);
  union VU { ushort4 v; unsigned short s[4]; };
  VU v4a[4], v4b[4];

  const int krow = w * 16 + (lane >> 3);
  const int kcb = (lane & 7) * 16;

#define STAGE_K(kt, dst)                                                      \
  {                                                                           \
    _Pragma("unroll") for (int i = 0; i < 2; ++i) {                           \
      const int row = krow + i * 8;                                           \
      gload_lds16((const char*)Kp + ((size_t)((kt)*64 + row) * 128 +          \
                                     SWZ(row, kcb)),                          \
                  (char*)(dst) + (w * 16 + i * 8) * 128);                     \
    }                                                                         \
  }
#define LOAD_V(kt, r)                                                         \
  {                                                                           \
    _Pragma("unroll") for (int j = 0; j < 4; ++j) (r)[j].v =                  \
        *(const ushort4*)(Vp + (size_t)((kt)*64 + bkv + j) * 64 + bd);        \
  }
#define WRITE_V(dst, r)                                                       \
  {                                                                           \
    _Pragma("unroll") for (int i = 0; i < 4; ++i) {                           \
      VU o4;                                                                  \
      _Pragma("unroll") for (int j = 0; j < 4; ++j) o4.s[j] = (r)[j].s[i];    \
      const int row = bd + i;                                                 \
      *(ushort4*)((char*)(dst) + row * 128 + SWZ(row, sbk)) = o4.v;           \
    }                                                                         \
  }

  union PU { bf16x8 v; unsigned u[4]; };

  auto compute_tile = [&](int kt, const char* kb, const char* vb) {
    const bool aAct = (kt <= qiA);
    bf16x8 kf[4][2];
#pragma unroll
    for (int c = 0; c < 4; ++c) {
      const int row = c * 16 + fr;
      const char* rp = kb + row * 128;
      kf[c][0] = *(const bf16x8*)(rp + SWZ(row, fg * 16));
      kf[c][1] = *(const bf16x8*)(rp + SWZ(row, 64 + fg * 16));
    }
    // V^T fragments: sigma layout makes each (ks,fg) fragment contiguous 16B
    bf16x8 vf[4][2];
#pragma unroll
    for (int d = 0; d < 4; ++d) {
      const int row = d * 16 + fr;
      const char* rp = vb + row * 128;
#pragma unroll
      for (int ks = 0; ks < 2; ++ks)
        vf[d][ks] = *(const bf16x8*)(rp + SWZ(row, ks * 64 + fg * 16));
    }

    auto strip_sm = [&](const bf16x8 (&qf)[2], float& s, bool diag,
                        PU (&pa)[2]) {
      f32x4 sc[4];
      __builtin_amdgcn_s_setprio(1);
#pragma unroll
      for (int c = 0; c < 4; ++c) {
        f32x4 acc = (f32x4){0.f, 0.f, 0.f, 0.f};
        acc = MFMA16(kf[c][0], qf[0], acc);  // C[kv][q]
        acc = MFMA16(kf[c][1], qf[1], acc);
        sc[c] = acc;
      }
      __builtin_amdgcn_s_setprio(0);
      float pv[4][4];
#pragma unroll
      for (int c = 0; c < 4; ++c)
#pragma unroll
        for (int r = 0; r < 4; ++r) {
          float sv = sc[c][r];
          if (diag) {
            const int kvloc = c * 16 + fg * 4 + r;
            sv = (kvloc <= qloc) ? sv : -INFINITY;
          }
          const float e = __builtin_amdgcn_exp2f(sv - MS);
          pv[c][r] = e;
          s += e;
        }
#pragma unroll
      for (int ks = 0; ks < 2; ++ks) {
        pa[ks].u[0] = cvtpk(pv[ks * 2][0], pv[ks * 2][1]);
        pa[ks].u[1] = cvtpk(pv[ks * 2][2], pv[ks * 2][3]);
        pa[ks].u[2] = cvtpk(pv[ks * 2 + 1][0], pv[ks * 2 + 1][1]);
        pa[ks].u[3] = cvtpk(pv[ks * 2 + 1][2], pv[ks * 2 + 1][3]);
      }
    };

    PU paA[2], paB[2];
    strip_sm(qB, sB, kt == qiB, paB);
    if (aAct) strip_sm(qA, sA, kt == qiA, paA);

    __builtin_amdgcn_s_setprio(1);
#pragma unroll
    for (int d = 0; d < 4; ++d) {
      oB[d] = MFMA16(paB[0].v, vf[d][0], oB[d]);
      oB[d] = MFMA16(paB[1].v, vf[d][1], oB[d]);
    }
    if (aAct) {
#pragma unroll
      for (int d = 0; d < 4; ++d) {
        oA[d] = MFMA16(paA[0].v, vf[d][0], oA[d]);
        oA[d] = MFMA16(paA[1].v, vf[d][1], oA[d]);
      }
    }
    __builtin_amdgcn_s_setprio(0);
  };

  // prologue: stage tiles 0,1 into buf 0 (NKV >= 9, both exist)
  STAGE_K(0, &Ksm[0][0][0]);
  STAGE_K(1, &Ksm[0][1][0]);
  LOAD_V(0, v4a);
  LOAD_V(1, v4b);
  WRITE_V(&Vts[0][0][0], v4a);
  WRITE_V(&Vts[0][1][0], v4b);
  __syncthreads();

  const int I = (NKV + 1) >> 1;
  for (int it = 0; it < I; ++it) {
    const int kt0 = 2 * it;
    const int b = it & 1;
    const bool more0 = (kt0 + 2 < NKV);
    const bool more1 = (kt0 + 3 < NKV);
    if (more0) {
      STAGE_K(kt0 + 2, &Ksm[b ^ 1][0][0]);
      LOAD_V(kt0 + 2, v4a);
    }
    if (more1) {
      STAGE_K(kt0 + 3, &Ksm[b ^ 1][1][0]);
      LOAD_V(kt0 + 3, v4b);
    }

    compute_tile(kt0, (const char*)&Ksm[b][0][0], (const char*)&Vts[b][0][0]);
    if (kt0 + 1 < NKV)
      compute_tile(kt0 + 1, (const char*)&Ksm[b][1][0],
                   (const char*)&Vts[b][1][0]);

    if (more0) WRITE_V(&Vts[b ^ 1][0][0], v4a);
    if (more1) WRITE_V(&Vts[b ^ 1][1][0], v4b);
    __syncthreads();
  }

  // ---- reduce row sums across fg groups: lane (*, fr) -> s[q=fr] ----
  sA += __shfl_xor(sA, 16); sA += __shfl_xor(sA, 32);
  sB += __shfl_xor(sB, 16); sB += __shfl_xor(sB, 32);
  float sAo[4], sBo[4];
#pragma unroll
  for (int r = 0; r < 4; ++r) {
    sAo[r] = __shfl(sA, fg * 4 + r);
    sBo[r] = __shfl(sB, fg * 4 + r);
  }

#pragma unroll
  for (int d = 0; d < 4; ++d)
#pragma unroll
    for (int r = 0; r < 4; ++r) {
      const float vA = oA[d][r] / sAo[r];
      const float vB = oB[d][r] / sBo[r];
      *(unsigned short*)&Op[(size_t)(rA0 + fg * 4 + r) * 64 + d * 16 + fr] =
          f2b(vA);
      *(unsigned short*)&Op[(size_t)(rB0 + fg * 4 + r) * 64 + d * 16 + fr] =
          f2b(vB);
    }
#undef STAGE_K
#undef LOAD_V
#undef WRITE_V
}

extern "C" void kernel_launch(void* const* d_in, const int* in_sizes, int n_in,
                              void* d_out, int out_size, void* d_ws,
                              size_t ws_size, hipStream_t stream) {
  const float* x = (const float*)d_in[0];
  const float* wq = (const float*)d_in[1];
  const float* wk = (const float*)d_in[2];
  const float* wv = (const float*)d_in[3];
  const float* wo = (const float*)d_in[4];
  float* out = (float*)d_out;
  char* ws = (char*)d_ws;

  bf16* xb = (bf16*)(ws);                  // 8 MB (4096x1024)
  bf16* wqkv = (bf16*)(ws + (8u << 20));   // 6 MB: wq|wk|wv = [3072][1024]
  bf16* wqb = wqkv;
  bf16* wkb = (bf16*)(ws + (10u << 20));
  bf16* wvb = (bf16*)(ws + (12u << 20));
  bf16* wob = (bf16*)(ws + (14u << 20));   // 2 MB
  bf16* qbuf = (bf16*)(ws + (16u << 20));  // 8 MB
  bf16* kbuf = (bf16*)(ws + (24u << 20));  // 8 MB
  bf16* vbuf = (bf16*)(ws + (32u << 20));  // 8 MB
  bf16* weib = (bf16*)(ws);                // reuse xb region after QKV GEMM

  cast_all<<<8192, 256, 0, stream>>>(x, wq, wk, wv, wo, (unsigned short*)xb,
                                     (unsigned short*)wqb, (unsigned short*)wkb,
                                     (unsigned short*)wvb, (unsigned short*)wob);
  gemm_qkv<<<dim3(32, 24), 256, 0, stream>>>(xb, wqkv, qbuf, kbuf, vbuf);
  attn_fwd<<<dim3(64, 8), 256, 0, stream>>>(qbuf, kbuf, vbuf, weib);
  gemm_out64<<<dim3(32, 16), 256, 0, stream>>>(weib, wob, out);
}

// Round 16
// 84.373 us; speedup vs baseline: 1.1279x; 1.0074x over previous
//
#include <hip/hip_runtime.h>
#include <hip/hip_bf16.h>

using bf16 = __hip_bfloat16;
typedef __attribute__((ext_vector_type(8))) short bf16x8;
typedef __attribute__((ext_vector_type(4))) float f32x4;

#define MFMA16(a, b, c) __builtin_amdgcn_mfma_f32_16x16x32_bf16(a, b, c, 0, 0, 0)
// XOR swizzle: spreads 8 rows of a 128B-stride tile across 8 16B slots
#define SWZ(row, byteoff) ((byteoff) ^ (((row) & 7) << 4))

__device__ __forceinline__ unsigned short f2b(float f) {
  union { float f; unsigned int u; } c; c.f = f;
  unsigned int r = c.u + 0x7fffu + ((c.u >> 16) & 1u);
  return (unsigned short)(r >> 16);
}
__device__ __forceinline__ float b2f(short b) {
  union { unsigned int u; float f; } c;
  c.u = ((unsigned int)(unsigned short)b) << 16;
  return c.f;
}
__device__ __forceinline__ bf16x8 scale8(bf16x8 v, float s) {
  bf16x8 r;
#pragma unroll
  for (int j = 0; j < 8; ++j) r[j] = (short)f2b(b2f(v[j]) * s);
  return r;
}
// packed f32x2 -> bf16x2 (T12 recipe: no builtin on gfx950, inline asm; RNE)
__device__ __forceinline__ unsigned cvtpk(float a, float b) {
  unsigned r;
  asm("v_cvt_pk_bf16_f32 %0, %1, %2" : "=v"(r) : "v"(a), "v"(b));
  return r;
}

__device__ __forceinline__ void gload_lds16(const void* g, void* l) {
  __builtin_amdgcn_global_load_lds(
      (const __attribute__((address_space(1))) void*)g,
      (__attribute__((address_space(3))) void*)l, 16, 0, 0);
}

__device__ __forceinline__ void store_out(float* p, float v) { *p = v; }
__device__ __forceinline__ void store_out(bf16* p, float v) {
  *(unsigned short*)p = f2b(v);
}

// ---------------- cast fp32 -> bf16 (x + 4 weights) ----------------
__global__ __launch_bounds__(256) void cast_all(
    const float* __restrict__ x, const float* __restrict__ wq,
    const float* __restrict__ wk, const float* __restrict__ wv,
    const float* __restrict__ wo,
    unsigned short* __restrict__ xb, unsigned short* __restrict__ wqb,
    unsigned short* __restrict__ wkb, unsigned short* __restrict__ wvb,
    unsigned short* __restrict__ wob) {
  int i = blockIdx.x * 256 + threadIdx.x;  // float4 units, 2097152 total
  const float* src;
  unsigned short* dst;
  int off;
  if (i < 1048576) {
    src = x; dst = xb; off = i;
  } else {
    int j = i - 1048576;
    int seg = j >> 18;
    off = j & 262143;
    src = (seg == 0) ? wq : (seg == 1) ? wk : (seg == 2) ? wv : wo;
    dst = (seg == 0) ? wqb : (seg == 1) ? wkb : (seg == 2) ? wvb : wob;
  }
  float4 v = reinterpret_cast<const float4*>(src)[off];
  ushort4 o;
  o.x = f2b(v.x); o.y = f2b(v.y); o.z = f2b(v.z); o.w = f2b(v.w);
  reinterpret_cast<ushort4*>(dst)[off] = o;
}

// ------- GEMM tile body: C[128][128] = A-rows @ Bt-rows^T, BK=64 ----------
// 128B LDS rows, XOR-swizzled. 32 MFMA per barrier-pair. (Session plateau
// structure: deep-pipeline attempts R6/R14 both regressed — frozen.)
template <typename TOUT>
__device__ __forceinline__ void gemm_tile(const bf16* __restrict__ A,
                                          const bf16* __restrict__ Bt,
                                          TOUT* __restrict__ C, int N, int K,
                                          int bm, int bn) {
  __shared__ bf16 Asm[128 * 64];  // 16 KB each
  __shared__ bf16 Bsm[128 * 64];
  const int tid = threadIdx.x;
  const int lane = tid & 63;
  const int w = tid >> 6;
  const int wr = w >> 1, wc = w & 1;
  const int fr = lane & 15;
  const int fg = lane >> 4;
  f32x4 acc[4][4] = {};

  const int strow = w * 8 + (lane >> 3);  // staging row within 32-row round
  const int stcb = (lane & 7) * 16;       // linear 16B slot within 128B row

  for (int kt = 0; kt < K; kt += 64) {
#pragma unroll
    for (int r = 0; r < 4; ++r) {
      const int row = r * 32 + strow;
      gload_lds16(
          (const char*)(A + (size_t)(bm + row) * K + kt) + SWZ(row, stcb),
          (char*)Asm + (r * 32 + w * 8) * 128);
      gload_lds16(
          (const char*)(Bt + (size_t)row * K + kt) + SWZ(row, stcb),
          (char*)Bsm + (r * 32 + w * 8) * 128);
    }
    __syncthreads();
    bf16x8 afr[4][2], bfr[4][2];
#pragma unroll
    for (int m = 0; m < 4; ++m) {
      const int row = wr * 64 + m * 16 + fr;
      const char* rp = (const char*)Asm + row * 128;
#pragma unroll
      for (int s = 0; s < 2; ++s)
        afr[m][s] = *(const bf16x8*)(rp + SWZ(row, s * 64 + fg * 16));
    }
#pragma unroll
    for (int n = 0; n < 4; ++n) {
      const int row = wc * 64 + n * 16 + fr;
      const char* rp = (const char*)Bsm + row * 128;
#pragma unroll
      for (int s = 0; s < 2; ++s)
        bfr[n][s] = *(const bf16x8*)(rp + SWZ(row, s * 64 + fg * 16));
    }
    __builtin_amdgcn_s_setprio(1);
#pragma unroll
    for (int m = 0; m < 4; ++m)
#pragma unroll
      for (int n = 0; n < 4; ++n) {
        acc[m][n] = MFMA16(afr[m][0], bfr[n][0], acc[m][n]);
        acc[m][n] = MFMA16(afr[m][1], bfr[n][1], acc[m][n]);
      }
    __builtin_amdgcn_s_setprio(0);
    __syncthreads();
  }
#pragma unroll
  for (int m = 0; m < 4; ++m) {
    const int row0 = bm + wr * 64 + m * 16 + (lane >> 4) * 4;
#pragma unroll
    for (int n = 0; n < 4; ++n) {
      const int col = bn + wc * 64 + n * 16 + fr;
#pragma unroll
      for (int r = 0; r < 4; ++r)
        store_out(&C[(size_t)(row0 + r) * N + col], acc[m][n][r]);
    }
  }
}

// fused QKV: B3 = [3072][1024]; XCD-swizzled grid (768 blocks, 768%8==0)
__global__ __launch_bounds__(256) void gemm_qkv(
    const bf16* __restrict__ A, const bf16* __restrict__ B3,
    bf16* __restrict__ Cq, bf16* __restrict__ Ck, bf16* __restrict__ Cv) {
  const int id = blockIdx.y * 32 + blockIdx.x;   // 0..767
  const int sw = (id & 7) * 96 + (id >> 3);      // bijective XCD chunking
  const int bm = (sw & 31) * 128;
  const int bnG = (sw >> 5) * 128;
  bf16* C = (bnG < 1024) ? Cq : (bnG < 2048) ? Ck : Cv;
  gemm_tile<bf16>(A, B3 + (size_t)bnG * 1024, C, 1024, 1024, bm, bnG & 1023);
}

// ---- out-proj: 128x64 tiles, 512 blocks -> 2 blocks/CU ----
__global__ __launch_bounds__(256) void gemm_out64(const bf16* __restrict__ A,
                                                  const bf16* __restrict__ B,
                                                  float* __restrict__ C) {
  __shared__ bf16 Asm[128 * 64];  // 16 KB
  __shared__ bf16 Bsm[64 * 64];   // 8 KB
  const int id = blockIdx.y * 32 + blockIdx.x;  // 0..511
  const int sw = (id & 7) * 64 + (id >> 3);     // bijective XCD chunking
  const int bm = (sw & 31) * 128;
  const int bn = (sw >> 5) * 64;
  const bf16* Bt = B + (size_t)bn * 1024;

  const int tid = threadIdx.x;
  const int lane = tid & 63;
  const int w = tid >> 6;
  const int wr = w >> 1, wc = w & 1;
  const int fr = lane & 15;
  const int fg = lane >> 4;
  f32x4 acc[4][2] = {};

  const int strow = w * 8 + (lane >> 3);
  const int stcb = (lane & 7) * 16;

  for (int kt = 0; kt < 1024; kt += 64) {
#pragma unroll
    for (int r = 0; r < 4; ++r) {
      const int row = r * 32 + strow;
      gload_lds16(
          (const char*)(A + (size_t)(bm + row) * 1024 + kt) + SWZ(row, stcb),
          (char*)Asm + (r * 32 + w * 8) * 128);
    }
#pragma unroll
    for (int r = 0; r < 2; ++r) {
      const int row = r * 32 + strow;
      gload_lds16(
          (const char*)(Bt + (size_t)row * 1024 + kt) + SWZ(row, stcb),
          (char*)Bsm + (r * 32 + w * 8) * 128);
    }
    __syncthreads();
    bf16x8 afr[4][2], bfr[2][2];
#pragma unroll
    for (int m = 0; m < 4; ++m) {
      const int row = wr * 64 + m * 16 + fr;
      const char* rp = (const char*)Asm + row * 128;
#pragma unroll
      for (int s = 0; s < 2; ++s)
        afr[m][s] = *(const bf16x8*)(rp + SWZ(row, s * 64 + fg * 16));
    }
#pragma unroll
    for (int n = 0; n < 2; ++n) {
      const int row = wc * 32 + n * 16 + fr;
      const char* rp = (const char*)Bsm + row * 128;
#pragma unroll
      for (int s = 0; s < 2; ++s)
        bfr[n][s] = *(const bf16x8*)(rp + SWZ(row, s * 64 + fg * 16));
    }
    __builtin_amdgcn_s_setprio(1);
#pragma unroll
    for (int m = 0; m < 4; ++m)
#pragma unroll
      for (int n = 0; n < 2; ++n) {
        acc[m][n] = MFMA16(afr[m][0], bfr[n][0], acc[m][n]);
        acc[m][n] = MFMA16(afr[m][1], bfr[n][1], acc[m][n]);
      }
    __builtin_amdgcn_s_setprio(0);
    __syncthreads();
  }
#pragma unroll
  for (int m = 0; m < 4; ++m) {
    const int row0 = bm + wr * 64 + m * 16 + fg * 4;
#pragma unroll
    for (int n = 0; n < 2; ++n) {
      const int col = bn + wc * 32 + n * 16 + fr;
#pragma unroll
      for (int r = 0; r < 4; ++r)
        C[(size_t)(row0 + r) * 1024 + col] = acc[m][n][r];
    }
  }
}

// ---------------- causal flash attention, KVBLK=128, dual-stream ----------
// R15 structure + T15 tile-merge: both staged tiles of a group are computed
// in ONE straight-line region (4 independent QK+SM streams B0,B1,A0,A1),
// giving the scheduler >=2 streams even when strip A is inactive — SM VALU
// of one tile hides under the other tile's MFMA. PV accumulation order
// matches the old sequential order exactly -> bit-identical output.
// sigma V^T layout (contiguous b128 PV fragments); static-M softmax
// exp2(S*log2e-12); swapped QK^T; in-register P via cvt_pk.
__global__ __launch_bounds__(256) void attn_fwd(
    const bf16* __restrict__ Q, const bf16* __restrict__ K,
    const bf16* __restrict__ V, bf16* __restrict__ O) {
  const int nh = blockIdx.x;  // head-major
  const size_t base = (size_t)nh * 65536;  // 1024*64 contiguous per head
  const bf16* Qp = Q + base;
  const bf16* Kp = K + base;
  const bf16* Vp = V + base;
  bf16* Op = O + base;
  const int p = blockIdx.y;  // pair 0..7
  const int qiA = p, qiB = 15 - p;
  const int tid = threadIdx.x;
  const int lane = tid & 63;
  const int w = tid >> 6;
  const int fr = lane & 15;
  const int fg = lane >> 4;

  __shared__ __align__(16) bf16 Ksm[2][2][64 * 64];  // [buf][slot][kv][d]
  __shared__ __align__(16) bf16 Vts[2][2][64 * 64];  // [buf][slot][d][sigma]

  const float QSC = 0.125f * 1.44269504089f;  // exp2 domain
  const float MS = 12.0f;                     // static softmax shift
  const int rA0 = qiA * 64 + w * 16;
  const int rB0 = qiB * 64 + w * 16;
  bf16x8 qA[2], qB[2];
#pragma unroll
  for (int ks = 0; ks < 2; ++ks) {
    qA[ks] = scale8(
        *(const bf16x8*)&Qp[(size_t)(rA0 + fr) * 64 + ks * 32 + fg * 8], QSC);
    qB[ks] = scale8(
        *(const bf16x8*)&Qp[(size_t)(rB0 + fr) * 64 + ks * 32 + fg * 8], QSC);
  }

  float sA = 0.f, sB = 0.f;  // per-lane partial row-sum (row q = fr)
  f32x4 oA[4], oB[4];
#pragma unroll
  for (int d = 0; d < 4; ++d) {
    oA[d] = (f32x4){0.f, 0.f, 0.f, 0.f};
    oB[d] = (f32x4){0.f, 0.f, 0.f, 0.f};
  }

  const int NKV = qiB + 1;       // 9..16
  const int qloc = w * 16 + fr;  // tile-relative q-row of this lane

  // V transpose thread mapping; sigma-permuted column base for the 4-kv group
  const int bkv = (tid & 15) * 4;
  const int bd = (tid >> 4) * 4;
  const int sbk = ((bkv >> 5) << 6) + (((bkv >> 2) & 3) << 4) +
                  (((bkv >> 4) & 1) << 3);
  union VU { ushort4 v; unsigned short s[4]; };
  VU v4a[4], v4b[4];

  const int krow = w * 16 + (lane >> 3);
  const int kcb = (lane & 7) * 16;

#define STAGE_K(kt, dst)                                                      \
  {                                                                           \
    _Pragma("unroll") for (int i = 0; i < 2; ++i) {                           \
      const int row = krow + i * 8;                                           \
      gload_lds16((const char*)Kp + ((size_t)((kt)*64 + row) * 128 +          \
                                     SWZ(row, kcb)),                          \
                  (char*)(dst) + (w * 16 + i * 8) * 128);                     \
    }                                                                         \
  }
#define LOAD_V(kt, r)                                                         \
  {                                                                           \
    _Pragma("unroll") for (int j = 0; j < 4; ++j) (r)[j].v =                  \
        *(const ushort4*)(Vp + (size_t)((kt)*64 + bkv + j) * 64 + bd);        \
  }
#define WRITE_V(dst, r)                                                       \
  {                                                                           \
    _Pragma("unroll") for (int i = 0; i < 4; ++i) {                           \
      VU o4;                                                                  \
      _Pragma("unroll") for (int j = 0; j < 4; ++j) o4.s[j] = (r)[j].s[i];    \
      const int row = bd + i;                                                 \
      *(ushort4*)((char*)(dst) + row * 128 + SWZ(row, sbk)) = o4.v;           \
    }                                                                         \
  }

  union PU { bf16x8 v; unsigned u[4]; };

  // load K fragments of one tile
  auto load_kf = [&](const char* kb, bf16x8 (&kf)[4][2]) {
#pragma unroll
    for (int c = 0; c < 4; ++c) {
      const int row = c * 16 + fr;
      const char* rp = kb + row * 128;
      kf[c][0] = *(const bf16x8*)(rp + SWZ(row, fg * 16));
      kf[c][1] = *(const bf16x8*)(rp + SWZ(row, 64 + fg * 16));
    }
  };
  // load V^T fragments (sigma layout: contiguous 16B per fragment)
  auto load_vf = [&](const char* vb, bf16x8 (&vf)[4][2]) {
#pragma unroll
    for (int d = 0; d < 4; ++d) {
      const int row = d * 16 + fr;
      const char* rp = vb + row * 128;
#pragma unroll
      for (int ks = 0; ks < 2; ++ks)
        vf[d][ks] = *(const bf16x8*)(rp + SWZ(row, ks * 64 + fg * 16));
    }
  };
  // swapped QK^T + static-M softmax + in-register P pack for one strip/tile
  auto qk_sm = [&](const bf16x8 (&kf)[4][2], const bf16x8 (&qf)[2], float& s,
                   bool diag, PU (&pa)[2]) {
    f32x4 sc[4];
    __builtin_amdgcn_s_setprio(1);
#pragma unroll
    for (int c = 0; c < 4; ++c) {
      f32x4 acc = (f32x4){0.f, 0.f, 0.f, 0.f};
      acc = MFMA16(kf[c][0], qf[0], acc);  // C[kv][q]
      acc = MFMA16(kf[c][1], qf[1], acc);
      sc[c] = acc;
    }
    __builtin_amdgcn_s_setprio(0);
    float pv[4][4];
#pragma unroll
    for (int c = 0; c < 4; ++c)
#pragma unroll
      for (int r = 0; r < 4; ++r) {
        float sv = sc[c][r];
        if (diag) {
          const int kvloc = c * 16 + fg * 4 + r;
          sv = (kvloc <= qloc) ? sv : -INFINITY;
        }
        const float e = __builtin_amdgcn_exp2f(sv - MS);
        pv[c][r] = e;
        s += e;
      }
#pragma unroll
    for (int ks = 0; ks < 2; ++ks) {
      pa[ks].u[0] = cvtpk(pv[ks * 2][0], pv[ks * 2][1]);
      pa[ks].u[1] = cvtpk(pv[ks * 2][2], pv[ks * 2][3]);
      pa[ks].u[2] = cvtpk(pv[ks * 2 + 1][0], pv[ks * 2 + 1][1]);
      pa[ks].u[3] = cvtpk(pv[ks * 2 + 1][2], pv[ks * 2 + 1][3]);
    }
  };
  auto pv_acc = [&](const PU (&pa)[2], const bf16x8 (&vf)[4][2],
                    f32x4 (&o)[4]) {
    __builtin_amdgcn_s_setprio(1);
#pragma unroll
    for (int d = 0; d < 4; ++d) {
      o[d] = MFMA16(pa[0].v, vf[d][0], o[d]);
      o[d] = MFMA16(pa[1].v, vf[d][1], o[d]);
    }
    __builtin_amdgcn_s_setprio(0);
  };

  // single-tile path (tail)
  auto compute_tile = [&](int kt, const char* kb, const char* vb) {
    const bool aAct = (kt <= qiA);
    bf16x8 kf[4][2], vf[4][2];
    load_kf(kb, kf);
    load_vf(vb, vf);
    PU paA[2], paB[2];
    qk_sm(kf, qB, sB, kt == qiB, paB);
    if (aAct) qk_sm(kf, qA, sA, kt == qiA, paA);
    pv_acc(paB, vf, oB);
    if (aAct) pv_acc(paA, vf, oA);
  };

  // dual-tile merged path: 4 independent QK/SM streams, then PVs in the
  // SAME o-accumulation order as sequential tiles (B0,A0,B1,A1 per-o).
  auto compute_pair = [&](int kt0, const char* kb0, const char* vb0,
                          const char* kb1, const char* vb1) {
    const int kt1 = kt0 + 1;
    const bool a0 = (kt0 <= qiA), a1 = (kt1 <= qiA);
    bf16x8 kf0[4][2], kf1[4][2];
    load_kf(kb0, kf0);
    load_kf(kb1, kf1);
    PU paB0[2], paB1[2], paA0[2], paA1[2];
    qk_sm(kf0, qB, sB, kt0 == qiB, paB0);
    qk_sm(kf1, qB, sB, kt1 == qiB, paB1);
    if (a0) qk_sm(kf0, qA, sA, kt0 == qiA, paA0);
    if (a1) qk_sm(kf1, qA, sA, kt1 == qiA, paA1);
    bf16x8 vf[4][2];
    load_vf(vb0, vf);
    pv_acc(paB0, vf, oB);        // oB += B0
    if (a0) pv_acc(paA0, vf, oA);  // oA += A0
    load_vf(vb1, vf);
    pv_acc(paB1, vf, oB);        // oB += B1
    if (a1) pv_acc(paA1, vf, oA);  // oA += A1
  };

  // prologue: stage tiles 0,1 into buf 0 (NKV >= 9, both exist)
  STAGE_K(0, &Ksm[0][0][0]);
  STAGE_K(1, &Ksm[0][1][0]);
  LOAD_V(0, v4a);
  LOAD_V(1, v4b);
  WRITE_V(&Vts[0][0][0], v4a);
  WRITE_V(&Vts[0][1][0], v4b);
  __syncthreads();

  const int I = (NKV + 1) >> 1;
  for (int it = 0; it < I; ++it) {
    const int kt0 = 2 * it;
    const int b = it & 1;
    const bool more0 = (kt0 + 2 < NKV);
    const bool more1 = (kt0 + 3 < NKV);
    if (more0) {
      STAGE_K(kt0 + 2, &Ksm[b ^ 1][0][0]);
      LOAD_V(kt0 + 2, v4a);
    }
    if (more1) {
      STAGE_K(kt0 + 3, &Ksm[b ^ 1][1][0]);
      LOAD_V(kt0 + 3, v4b);
    }

    if (kt0 + 1 < NKV)
      compute_pair(kt0, (const char*)&Ksm[b][0][0], (const char*)&Vts[b][0][0],
                   (const char*)&Ksm[b][1][0], (const char*)&Vts[b][1][0]);
    else
      compute_tile(kt0, (const char*)&Ksm[b][0][0],
                   (const char*)&Vts[b][0][0]);

    if (more0) WRITE_V(&Vts[b ^ 1][0][0], v4a);
    if (more1) WRITE_V(&Vts[b ^ 1][1][0], v4b);
    __syncthreads();
  }

  // ---- reduce row sums across fg groups: lane (*, fr) -> s[q=fr] ----
  sA += __shfl_xor(sA, 16); sA += __shfl_xor(sA, 32);
  sB += __shfl_xor(sB, 16); sB += __shfl_xor(sB, 32);
  float sAo[4], sBo[4];
#pragma unroll
  for (int r = 0; r < 4; ++r) {
    sAo[r] = __shfl(sA, fg * 4 + r);
    sBo[r] = __shfl(sB, fg * 4 + r);
  }

#pragma unroll
  for (int d = 0; d < 4; ++d)
#pragma unroll
    for (int r = 0; r < 4; ++r) {
      const float vA = oA[d][r] / sAo[r];
      const float vB = oB[d][r] / sBo[r];
      *(unsigned short*)&Op[(size_t)(rA0 + fg * 4 + r) * 64 + d * 16 + fr] =
          f2b(vA);
      *(unsigned short*)&Op[(size_t)(rB0 + fg * 4 + r) * 64 + d * 16 + fr] =
          f2b(vB);
    }
#undef STAGE_K
#undef LOAD_V
#undef WRITE_V
}

extern "C" void kernel_launch(void* const* d_in, const int* in_sizes, int n_in,
                              void* d_out, int out_size, void* d_ws,
                              size_t ws_size, hipStream_t stream) {
  const float* x = (const float*)d_in[0];
  const float* wq = (const float*)d_in[1];
  const float* wk = (const float*)d_in[2];
  const float* wv = (const float*)d_in[3];
  const float* wo = (const float*)d_in[4];
  float* out = (float*)d_out;
  char* ws = (char*)d_ws;

  bf16* xb = (bf16*)(ws);                  // 8 MB (4096x1024)
  bf16* wqkv = (bf16*)(ws + (8u << 20));   // 6 MB: wq|wk|wv = [3072][1024]
  bf16* wqb = wqkv;
  bf16* wkb = (bf16*)(ws + (10u << 20));
  bf16* wvb = (bf16*)(ws + (12u << 20));
  bf16* wob = (bf16*)(ws + (14u << 20));   // 2 MB
  bf16* qbuf = (bf16*)(ws + (16u << 20));  // 8 MB
  bf16* kbuf = (bf16*)(ws + (24u << 20));  // 8 MB
  bf16* vbuf = (bf16*)(ws + (32u << 20));  // 8 MB
  bf16* weib = (bf16*)(ws);                // reuse xb region after QKV GEMM

  cast_all<<<8192, 256, 0, stream>>>(x, wq, wk, wv, wo, (unsigned short*)xb,
                                     (unsigned short*)wqb, (unsigned short*)wkb,
                                     (unsigned short*)wvb, (unsigned short*)wob);
  gemm_qkv<<<dim3(32, 24), 256, 0, stream>>>(xb, wqkv, qbuf, kbuf, vbuf);
  attn_fwd<<<dim3(64, 8), 256, 0, stream>>>(qbuf, kbuf, vbuf, weib);
  gemm_out64<<<dim3(32, 16), 256, 0, stream>>>(weib, wob, out);
}